// Round 3
// baseline (37.700 us; speedup 1.0000x reference)
//
#include <hip/hip_runtime.h>
#include <hip/hip_bf16.h>

typedef __attribute__((ext_vector_type(8))) short bf16x8;
typedef __attribute__((ext_vector_type(16))) float f32x16;

#define CC 128
#define KK 128
#define HH 56
#define WW 56
#define HW (HH * WW)

// workspace layout
#define WT_OFF 0
#define XP_OFF (512 * 1024)

__device__ __forceinline__ unsigned short f2bf(float f) {
  unsigned int u = __builtin_bit_cast(unsigned int, f);
  u += 0x7FFFu + ((u >> 16) & 1u);
  return (unsigned short)(u >> 16);
}

__device__ __forceinline__ void gload_lds16(const void* g, void* l) {
  __builtin_amdgcn_global_load_lds((__attribute__((address_space(1))) void*)g,
                                   (__attribute__((address_space(3))) void*)l,
                                   16, 0, 0);
}

// K1: kernel (K,C,3,3) f32 -> wt2, A-fragment order:
// wt2[((m*4+cs)*4+kf)*512 + lane*8 + j]
//   m=ch*9+rs, k=kf*32+(lane&31), c=ch*64+cs*16+(lane>>5)*8+j
__global__ void wtrans_kernel(const float* __restrict__ kin,
                              unsigned short* __restrict__ wt2) {
  int idx = blockIdx.x * 256 + threadIdx.x;  // 147456 exact
  int j = idx & 7;
  int l = (idx >> 3) & 63;
  int kf = (idx >> 9) & 3;
  int cs = (idx >> 11) & 3;
  int m = idx >> 13;  // 0..17
  int ch = (m >= 9) ? 1 : 0;
  int rs = m - ch * 9;
  int k = kf * 32 + (l & 31);
  int c = ch * 64 + cs * 16 + (l >> 5) * 8 + j;
  wt2[idx] = f2bf(kin[(k * CC + c) * 9 + rs]);
}

// K2: x fp32 NCHW -> xp bf16 [n][co(16)][h(58)][w(64)][ci(8)], zero-padded
// at h=0,57 and w=0,57..63. 950272 cells of 16B.
__global__ void prepack_kernel(const float* __restrict__ x,
                               unsigned short* __restrict__ xp) {
  int idx = blockIdx.x * 256 + threadIdx.x;  // 950272 exact
  int w = idx & 63;
  int r = idx >> 6;
  int h = r % 58;
  int t = r / 58;  // n*16+co ; channel base = t*8
  bool ok = (w >= 1) && (w <= 56) && (h >= 1) && (h <= 56);
  const float* src = x + (size_t)t * 8 * HW + (h - 1) * WW + (w - 1);
  unsigned short o[8];
#pragma unroll
  for (int ci = 0; ci < 8; ++ci) {
    float v = ok ? src[ci * HW] : 0.f;
    o[ci] = f2bf(v);
  }
  *(bf16x8*)(xp + (size_t)idx * 8) = *(bf16x8*)o;
}

// K3: direct 3x3 conv as implicit GEMM, bf16 MFMA 32x32x16.
// Block 512 thr (8 waves), tile 128k x (4 rows x 56 w), grid 14x16.
// LDS: ping-pong 2 x [6 rows][64 cols][64ch] bf16 (96KB), staged entirely in
// the prologue via global_load_lds (source pre-swizzled in xp).
// Wave (kp, sh): 2 kfrags x {2,2,2,1} sfrags.
__global__ __launch_bounds__(512, 2) void conv_kernel(
    const unsigned short* __restrict__ xp, const unsigned short* __restrict__ wt2,
    float* __restrict__ out) {
  __shared__ __align__(16) unsigned char xs[2 * 6 * 64 * 128];  // 98304 B

  const int tid = threadIdx.x;
  const int lane = tid & 63;
  const int wv = tid >> 6;    // 0..7
  const int bh = blockIdx.x;  // 0..13
  const int n = blockIdx.y;   // 0..15
  const int r0 = bh * 4;

  const int p = lane & 31;
  const int dr = p >> 3;
  const int dw = p & 7;
  const int hi = lane >> 5;

  const int kp = wv >> 2;
  const int sh = wv & 3;
  const int ns = (sh == 3) ? 1 : 2;
  const int s0 = sh * 2;

  // ---- prologue: stage BOTH channel phases, async ----
  // wave wv stages column-group g=wv, rows 0..5. Lane l covers LDS
  // (col=g*8+(l>>3), slot=l&7); source oct = slot ^ (col&7) pre-swizzles.
  {
    const int oct = (lane & 7) ^ ((lane >> 3) & 7);
    const int col = wv * 8 + (lane >> 3);
    const unsigned short* g0 =
        xp + ((((size_t)n * 16 + oct) * 58 + r0) * 64 + col) * 8;
#pragma unroll
    for (int ch = 0; ch < 2; ++ch) {
#pragma unroll
      for (int lr = 0; lr < 6; ++lr) {
        gload_lds16(g0 + ch * (8 * 58 * 64 * 8) + lr * 512,
                    xs + ch * 49152 + lr * 8192 + wv * 1024);
      }
    }
  }

  f32x16 acc[2][2] = {};  // [kfl][si]
  bf16x8 A0[8], A1[8];    // [cs*2+kfl]

  auto ldA = [&](int step, bf16x8* D) {
#pragma unroll
    for (int cs = 0; cs < 4; ++cs)
#pragma unroll
      for (int kfl = 0; kfl < 2; ++kfl)
        D[cs * 2 + kfl] = *(const bf16x8*)(
            wt2 + (((step * 4 + cs) * 4 + kp * 2 + kfl) << 9) + lane * 8);
  };

  // wait own phase-0 loads (6 newest are phase-1), all waves, then barrier
  asm volatile("s_waitcnt vmcnt(6)" ::: "memory");
  __builtin_amdgcn_s_barrier();
  asm volatile("" ::: "memory");

  ldA(0, A0);

  auto phase = [&](const int ch, const unsigned char* buf) {
#pragma unroll
    for (int rs = 0; rs < 9; ++rs) {
      const int step = ch * 9 + rs;
      bf16x8* Ac = (step & 1) ? A1 : A0;
      bf16x8* An = (step & 1) ? A0 : A1;
      if (step < 17) ldA(step + 1, An);
      const int fr = (rs * 11) >> 5;  // rs/3
      const int fs = rs - fr * 3;
      const int rbase = ((dr + fr) * 64 + dw + fs) << 7;
      const int xr = (dw + fs) & 7;
#pragma unroll
      for (int cs = 0; cs < 4; ++cs) {
        const int sb = rbase + ((((cs << 1) + hi) ^ xr) << 4);
#pragma unroll
        for (int si = 0; si < 2; ++si) {
          if (si < ns) {
            bf16x8 b = *(const bf16x8*)(buf + sb + (s0 + si) * 1024);
            acc[0][si] = __builtin_amdgcn_mfma_f32_32x32x16_bf16(
                Ac[cs * 2 + 0], b, acc[0][si], 0, 0, 0);
            acc[1][si] = __builtin_amdgcn_mfma_f32_32x32x16_bf16(
                Ac[cs * 2 + 1], b, acc[1][si], 0, 0, 0);
          }
        }
      }
    }
  };

  phase(0, xs);
  __syncthreads();  // drains vmcnt(0): phase-1 staging complete block-wide
  phase(1, xs + 49152);

  // ---- epilogue: C/D frag col=lane&31 -> spatial; row=(r&3)+8*(r>>2)+4*hi
#pragma unroll
  for (int kfl = 0; kfl < 2; ++kfl) {
#pragma unroll
    for (int si = 0; si < 2; ++si) {
      if (si < ns) {
        const int s = s0 + si;
#pragma unroll
        for (int r = 0; r < 16; ++r) {
          const int krow =
              kp * 64 + kfl * 32 + (r & 3) + ((r >> 2) << 3) + (hi << 2);
          out[(((size_t)n * KK + krow) * HH + (r0 + dr)) * WW + s * 8 + dw] =
              acc[kfl][si][r];
        }
      }
    }
  }
}

extern "C" void kernel_launch(void* const* d_in, const int* in_sizes, int n_in,
                              void* d_out, int out_size, void* d_ws, size_t ws_size,
                              hipStream_t stream) {
  const float* x = (const float*)d_in[0];
  const float* kin = (const float*)d_in[1];
  float* out = (float*)d_out;
  unsigned short* wt2 = (unsigned short*)((char*)d_ws + WT_OFF);  // 288 KB
  unsigned short* xp = (unsigned short*)((char*)d_ws + XP_OFF);   // 15.2 MB

  hipLaunchKernelGGL(prepack_kernel, dim3(3712), dim3(256), 0, stream, x, xp);
  hipLaunchKernelGGL(wtrans_kernel, dim3(576), dim3(256), 0, stream, kin, wt2);
  hipLaunchKernelGGL(conv_kernel, dim3(14, 16), dim3(512), 0, stream, xp, wt2, out);
}